// Round 1
// baseline (6369.375 us; speedup 1.0000x reference)
//
#include <hip/hip_runtime.h>

#define NPTS   40000
#define NG     4
#define NK     64
#define ND     400
#define PT     256          // points per tile
#define BK     16           // d-chunk size
#define NCHUNK 25           // ND / BK
#define NTILES 157          // ceil(NPTS / PT)
#define BPG    64           // blocks per group

// Fused assignment + accumulation kernel. One block handles `tile = bx, bx+64, ...`
// tiles of 256 points for group g, accumulating per-cluster sums in LDS, then
// writes a deterministic per-block partial sum (no global float atomics).
__global__ __launch_bounds__(256)
void assign_kernel(const float* __restrict__ patches,   // [NPTS][NG][ND]
                   const float* __restrict__ cent,      // [NG][NK][ND]
                   float* __restrict__ psum,            // [NG][BPG][NK][ND]
                   int*   __restrict__ pcnt)            // [NG][BPG][NK]
{
    const int g  = blockIdx.y;
    const int bx = blockIdx.x;
    const int t  = threadIdx.x;

    __shared__ float sums[NK][ND + 1];      // 102656 B, stride 401 (odd mod 32)
    __shared__ float pT[BK][PT];            // 16 KB, [d][n]
    __shared__ float cT[BK][NK];            // 4 KB,  [d][k]
    __shared__ float xmax[8][PT];           // 8 KB
    __shared__ int   xidx[8][PT];           // 8 KB
    __shared__ int   labels[PT];            // 1 KB
    __shared__ int   cnt[NK];
    __shared__ float c2s[NK];

    for (int i = t; i < NK * (ND + 1); i += 256) (&sums[0][0])[i] = 0.0f;
    if (t < NK) cnt[t] = 0;

    // 0.5 * ||c_k||^2, sequential over d (matches reference reduction closely)
    if (t < NK) {
        const float* c = cent + ((size_t)g * NK + t) * ND;
        float s = 0.0f;
        for (int d = 0; d < ND; ++d) { float v = c[d]; s = fmaf(v, v, s); }
        c2s[t] = 0.5f * s;
    }
    __syncthreads();

    const int pq = t & 31;   // point-quad id: owns points 4*pq.. and 128+4*pq..
    const int cg = t >> 5;   // cluster group: owns clusters 8*cg..8*cg+7

    for (int tile = bx; tile < NTILES; tile += BPG) {
        const int n0 = tile * PT;

        float acc[8][8];
        #pragma unroll
        for (int i = 0; i < 8; ++i)
            #pragma unroll
            for (int j = 0; j < 8; ++j) acc[i][j] = 0.0f;

        float4 pp[4]; float4 pc;
        // prefetch chunk 0 into registers
        #pragma unroll
        for (int s = 0; s < 4; ++s) {
            int flat = t + 256 * s, n = flat >> 2, j = flat & 3;
            int nn = n0 + n; if (nn >= NPTS) nn = NPTS - 1;
            pp[s] = *(const float4*)(patches + ((size_t)nn * NG + g) * ND + 4 * j);
        }
        {
            int k = t >> 2, j = t & 3;
            pc = *(const float4*)(cent + ((size_t)g * NK + k) * ND + 4 * j);
        }

        // ---- pass 1: scores GEMM over 25 d-chunks, register-prefetched ----
        for (int c = 0; c < NCHUNK; ++c) {
            #pragma unroll
            for (int s = 0; s < 4; ++s) {
                int flat = t + 256 * s, n = flat >> 2, j = flat & 3;
                pT[4 * j + 0][n] = pp[s].x;
                pT[4 * j + 1][n] = pp[s].y;
                pT[4 * j + 2][n] = pp[s].z;
                pT[4 * j + 3][n] = pp[s].w;
            }
            {
                int k = t >> 2, j = t & 3;
                cT[4 * j + 0][k] = pc.x;
                cT[4 * j + 1][k] = pc.y;
                cT[4 * j + 2][k] = pc.z;
                cT[4 * j + 3][k] = pc.w;
            }
            __syncthreads();

            if (c + 1 < NCHUNK) {
                const int d0 = (c + 1) * BK;
                #pragma unroll
                for (int s = 0; s < 4; ++s) {
                    int flat = t + 256 * s, n = flat >> 2, j = flat & 3;
                    int nn = n0 + n; if (nn >= NPTS) nn = NPTS - 1;
                    pp[s] = *(const float4*)(patches + ((size_t)nn * NG + g) * ND + d0 + 4 * j);
                }
                int k = t >> 2, j = t & 3;
                pc = *(const float4*)(cent + ((size_t)g * NK + k) * ND + d0 + 4 * j);
            }

            #pragma unroll
            for (int d = 0; d < BK; ++d) {
                float4 pa = *(const float4*)&pT[d][4 * pq];
                float4 pb = *(const float4*)&pT[d][128 + 4 * pq];
                float4 ca = *(const float4*)&cT[d][8 * cg];
                float4 cb = *(const float4*)&cT[d][8 * cg + 4];
                float pv[8] = {pa.x, pa.y, pa.z, pa.w, pb.x, pb.y, pb.z, pb.w};
                float cv[8] = {ca.x, ca.y, ca.z, ca.w, cb.x, cb.y, cb.z, cb.w};
                #pragma unroll
                for (int i = 0; i < 8; ++i)
                    #pragma unroll
                    for (int j = 0; j < 8; ++j)
                        acc[i][j] = fmaf(pv[i], cv[j], acc[i][j]);
            }
            __syncthreads();
        }

        // ---- argmax: first-max tie-break ascending k (matches jnp.argmax) ----
        #pragma unroll
        for (int i = 0; i < 8; ++i) {
            int p = (i < 4) ? (4 * pq + i) : (128 + 4 * pq + (i - 4));
            float m = -3.402823466e+38f; int best = 8 * cg;
            #pragma unroll
            for (int j = 0; j < 8; ++j) {
                float s = acc[i][j] - c2s[8 * cg + j];
                if (s > m) { m = s; best = 8 * cg + j; }
            }
            xmax[cg][p] = m; xidx[cg][p] = best;
        }
        __syncthreads();
        {
            float m = xmax[0][t]; int best = xidx[0][t];
            #pragma unroll
            for (int u = 1; u < 8; ++u) {
                float v = xmax[u][t];
                if (v > m) { m = v; best = xidx[u][t]; }
            }
            labels[t] = best;
            if (n0 + t < NPTS) atomicAdd(&cnt[best], 1);
        }
        __syncthreads();

        // ---- pass 2: re-stage (L2-hot) and scatter-add into LDS sums ----
        for (int c = 0; c < NCHUNK; ++c) {
            const int d0 = c * BK;
            #pragma unroll
            for (int s = 0; s < 4; ++s) {
                int flat = t + 256 * s, n = flat >> 2, j = flat & 3;
                int nn = n0 + n; if (nn >= NPTS) nn = NPTS - 1;
                float4 v = *(const float4*)(patches + ((size_t)nn * NG + g) * ND + d0 + 4 * j);
                pT[4 * j + 0][n] = v.x;
                pT[4 * j + 1][n] = v.y;
                pT[4 * j + 2][n] = v.z;
                pT[4 * j + 3][n] = v.w;
            }
            __syncthreads();
            if (n0 + t < NPTS) {
                float* srow = &sums[labels[t]][d0];
                #pragma unroll
                for (int d = 0; d < BK; ++d) atomicAdd(&srow[d], pT[d][t]);
            }
            __syncthreads();
        }
    }

    __syncthreads();
    // deterministic per-block partial output (no global float atomics)
    float* my = psum + (size_t)(g * BPG + bx) * NK * ND;
    for (int flat = t; flat < NK * ND; flat += 256) {
        int k = flat / ND, d = flat - k * ND;
        my[flat] = sums[k][d];
    }
    if (t < NK) pcnt[(g * BPG + bx) * NK + t] = cnt[t];
}

// Reduce 64 partials per (g,k), divide by counts (1 if empty), zero clusters
// empty in ANY group.
__global__ __launch_bounds__(256)
void update_kernel(const float* __restrict__ psum,
                   const int*   __restrict__ pcnt,
                   float* __restrict__ outc)            // [NG][NK][ND]
{
    const int gk = blockIdx.x;        // g*64 + k
    const int g = gk >> 6, k = gk & 63;
    const int t = threadIdx.x;

    __shared__ int cnts[NG];
    if (t < NG) cnts[t] = 0;
    __syncthreads();
    {
        int g2 = t >> 6, b = t & 63;  // 256 threads = 4 groups x 64 blocks
        atomicAdd(&cnts[g2], pcnt[(g2 * BPG + b) * NK + k]);
    }
    __syncthreads();
    const bool bad = (cnts[0] == 0) | (cnts[1] == 0) | (cnts[2] == 0) | (cnts[3] == 0);
    const int  myc = cnts[g];
    const float denom = (float)(myc == 0 ? 1 : myc);

    for (int d = t; d < ND; d += 256) {
        float s = 0.0f;
        for (int b = 0; b < BPG; ++b)
            s += psum[((size_t)(g * BPG + b) * NK + k) * ND + d];
        outc[(size_t)gk * ND + d] = bad ? 0.0f : (s / denom);
    }
}

extern "C" void kernel_launch(void* const* d_in, const int* in_sizes, int n_in,
                              void* d_out, int out_size, void* d_ws, size_t ws_size,
                              hipStream_t stream)
{
    const float* patches = (const float*)d_in[0];
    const float* cinit   = (const float*)d_in[1];
    float* out = (float*)d_out;

    const size_t CSZ = (size_t)NG * NK * ND;            // 102400 floats
    float* centA = (float*)d_ws;
    float* centB = centA + CSZ;
    float* psum  = centB + CSZ;                         // NG*BPG*NK*ND floats (26.2 MB)
    int*   pcnt  = (int*)(psum + (size_t)NG * BPG * NK * ND);

    hipMemcpyAsync(centA, cinit, CSZ * sizeof(float), hipMemcpyDeviceToDevice, stream);

    float* cur = centA; float* nxt = centB;
    for (int e = 0; e < 10; ++e) {
        assign_kernel<<<dim3(BPG, NG), 256, 0, stream>>>(patches, cur, psum, pcnt);
        update_kernel<<<dim3(NG * NK), 256, 0, stream>>>(psum, pcnt, nxt);
        float* tmp = cur; cur = nxt; nxt = tmp;
    }
    hipMemcpyAsync(out, cur, CSZ * sizeof(float), hipMemcpyDeviceToDevice, stream);
}